// Round 1
// baseline (2021.819 us; speedup 1.0000x reference)
//
#include <hip/hip_runtime.h>
#include <hip/hip_bf16.h>

// EdgeBlock: out[E,64] = relu([edge_attr | x[recv] | x[send] | u] @ W1 + b1) @ W2 + b2
// u is constant across edges -> folded into b1' by prep kernel. Effective K1 = 192.
//
// R1 change: eliminate the per-nc LDS transpose round-trip between GEMM1 and GEMM2.
// GEMM1 operands are SWAPPED: mfma(W1frag, collectedFrag) so D is transposed —
// lane m holds edge m's hidden values (rows=hidden, cols=edges). After bias+relu+
// bf16 pack, {c0[0..3], c1[0..3]} is directly the GEMM2 A-fragment, with the hidden
// dimension permuted by rho(q*8+t) = q*4+t (t<4) / 16+q*4+(t-4) (t>=4). The
// permutation is applied to W2's ROWS ONLY in the prep kernel (hidden layer is
// internal, so any consistent permutation is legal). W1/b1 order unchanged.

#define N_EDGES   800000
#define N_TILES   (N_EDGES / 16)
#define K1        192        // D_EDGE + 2*D_NODE (u folded into bias)
#define D_HID     256
#define D_OUT     64
#define W1T_LD    200        // 192 padded: 100 words ≡ 4 mod 32 -> conflict-free B-frag reads
#define W2T_LD    264        // 256 padded: 132 words ≡ 4 mod 32
#define WAVES_PB  16
#define BLOCK_T   (WAVES_PB * 64)
#define GRID_MAIN 256

typedef __attribute__((ext_vector_type(8))) short  short8;   // 8 bf16 = one MFMA A/B frag
typedef __attribute__((ext_vector_type(4))) float  floatx4;  // MFMA C/D frag

// workspace layout (bytes)
#define WS_W1T_OFF 0
#define WS_W2T_OFF (256 * W1T_LD * 2)               // 102400
#define WS_B1P_OFF (WS_W2T_OFF + 64 * W2T_LD * 2)   // 136192; total use 137216 B

static __device__ __forceinline__ unsigned short f2bf(float f) {
    // round-to-nearest-even fp32 -> bf16
    unsigned u = __builtin_bit_cast(unsigned, f);
    u += 0x7fffu + ((u >> 16) & 1u);
    return (unsigned short)(u >> 16);
}

static __device__ __forceinline__ short8 cvt8(const float* __restrict__ p) {
    // load 8 contiguous fp32 (16B-aligned) and convert to packed bf16x8
    const floatx4* p4 = (const floatx4*)p;
    floatx4 f0 = p4[0];
    floatx4 f1 = p4[1];
    union { short8 s8; unsigned short us[8]; } u;
    u.us[0] = f2bf(f0.x); u.us[1] = f2bf(f0.y); u.us[2] = f2bf(f0.z); u.us[3] = f2bf(f0.w);
    u.us[4] = f2bf(f1.x); u.us[5] = f2bf(f1.y); u.us[6] = f2bf(f1.z); u.us[7] = f2bf(f1.w);
    return u.s8;
}

// ---------------- prep: W1^T, W2^T (bf16, padded, W2 rows permuted), b1' ----------------
__global__ void edgeblk_prep(const float* __restrict__ W1, const float* __restrict__ b1,
                             const float* __restrict__ W2, const float* __restrict__ u,
                             unsigned short* __restrict__ w1t, unsigned short* __restrict__ w2t,
                             float* __restrict__ b1p) {
    int tid = blockIdx.x * blockDim.x + threadIdx.x;
    int nth = gridDim.x * blockDim.x;
    for (int j = tid; j < 256 * K1; j += nth) {        // w1t[n][k] = W1[k][n]
        int n = j / K1, k = j - n * K1;
        w1t[n * W1T_LD + k] = f2bf(W1[k * 256 + n]);
    }
    for (int j = tid; j < 64 * 256; j += nth) {        // w2t[m][k] = W2[perm(k)][m]
        int m = j >> 8, k = j & 255;
        int kap = k & 31, q = kap >> 3, t = kap & 7;
        int rho = (t < 4) ? (q * 4 + t) : (16 + q * 4 + (t - 4));
        int src = (k & ~31) + rho;                     // permuted hidden row
        w2t[m * W2T_LD + k] = f2bf(W2[src * 64 + m]);
    }
    for (int n = tid; n < 256; n += nth) {
        float s = b1[n];
        for (int t = 0; t < 16; ++t) s += u[t] * W1[(K1 + t) * 256 + n];
        b1p[n] = s;
    }
}

// ---------------- main fused kernel ----------------
__global__ __launch_bounds__(BLOCK_T) void edgeblk_mlp(
        const float* __restrict__ x, const float* __restrict__ edge_attr,
        const int* __restrict__ eidx,
        const unsigned short* __restrict__ w1t_g, const unsigned short* __restrict__ w2t_g,
        const float* __restrict__ b1p_g, const float* __restrict__ b2_g,
        float* __restrict__ out) {
    // LDS total: 102400 + 33792 + 1024 + 256 = 137,472 B (<= 160 KiB)
    __shared__ alignas(16) unsigned short sW1[256 * W1T_LD];
    __shared__ alignas(16) unsigned short sW2[64 * W2T_LD];
    __shared__ alignas(16) float sB1[256];
    __shared__ alignas(16) float sB2[64];

    // stage weights global -> LDS (coalesced uint4)
    {
        const uint4* s1 = (const uint4*)w1t_g;  uint4* d1 = (uint4*)sW1;
        for (int i = threadIdx.x; i < 256 * W1T_LD / 8; i += BLOCK_T) d1[i] = s1[i];
        const uint4* s2 = (const uint4*)w2t_g;  uint4* d2 = (uint4*)sW2;
        for (int i = threadIdx.x; i < 64 * W2T_LD / 8; i += BLOCK_T) d2[i] = s2[i];
        if (threadIdx.x < 256) sB1[threadIdx.x] = b1p_g[threadIdx.x];
        if (threadIdx.x < 64)  sB2[threadIdx.x] = b2_g[threadIdx.x];
    }
    __syncthreads();

    const int wid  = threadIdx.x >> 6;
    const int lane = threadIdx.x & 63;
    const int m    = lane & 15;      // MFMA A-row / B-col / D-col index
    const int quad = lane >> 4;      // k-group (A/B) or row-group (C/D)

    // per-lane output-bias copies (registers)
    float b2v[4];
#pragma unroll
    for (int nt = 0; nt < 4; ++nt) b2v[nt] = sB2[nt * 16 + m];

    const int gw = blockIdx.x * WAVES_PB + wid;
    const int NW = GRID_MAIN * WAVES_PB;

    for (int tile = gw; tile < N_TILES; tile += NW) {
        const int e    = tile * 16 + m;
        const int recv = eidx[N_EDGES + e];   // edge_index[1]
        const int send = eidx[e];             // edge_index[0]
        const float* pe = edge_attr + (long)e    * 64 + quad * 8;
        const float* pr = x         + (long)recv * 64 + quad * 8;
        const float* ps = x         + (long)send * 64 + quad * 8;

        // frags of collected[16 x 192]: lane holds edge m, k = kt*32+quad*8..+8
        // (used as the MFMA *B* operand in GEMM1 — B layout mirrors A layout)
        short8 A[6];
        A[0] = cvt8(pe);      A[1] = cvt8(pe + 32);
        A[2] = cvt8(pr);      A[3] = cvt8(pr + 32);
        A[4] = cvt8(ps);      A[5] = cvt8(ps + 32);

        floatx4 oacc[4];
#pragma unroll
        for (int nt = 0; nt < 4; ++nt) oacc[nt] = (floatx4){0.f, 0.f, 0.f, 0.f};

#pragma unroll
        for (int nc = 0; nc < 8; ++nc) {          // 32-wide chunk of the 256 hidden cols
            floatx4 c0 = (floatx4){0.f, 0.f, 0.f, 0.f};
            floatx4 c1 = (floatx4){0.f, 0.f, 0.f, 0.f};
#pragma unroll
            for (int kt = 0; kt < 6; ++kt) {      // K1 = 192 = 6*32
                short8 bA = *(const short8*)&sW1[(nc * 32      + m) * W1T_LD + kt * 32 + quad * 8];
                short8 bB = *(const short8*)&sW1[(nc * 32 + 16 + m) * W1T_LD + kt * 32 + quad * 8];
                // SWAPPED operands: D = W1chunk . collected^T  -> lane holds col = edge m
                c0 = __builtin_amdgcn_mfma_f32_16x16x32_bf16(bA, A[kt], c0, 0, 0, 0);
                c1 = __builtin_amdgcn_mfma_f32_16x16x32_bf16(bB, A[kt], c1, 0, 0, 0);
            }
            // bias (broadcast LDS reads) + relu + pack -> GEMM2 A-frag, all in registers.
            // c0[r] = hidden chunk-row quad*4+r, c1[r] = chunk-row 16+quad*4+r, edge m.
            const floatx4 bias0 = *(const floatx4*)&sB1[nc * 32      + quad * 4];
            const floatx4 bias1 = *(const floatx4*)&sB1[nc * 32 + 16 + quad * 4];
            union { short8 s8; unsigned short us[8]; } a2u;
#pragma unroll
            for (int r = 0; r < 4; ++r) {
                float h0 = c0[r] + bias0[r];
                float h1 = c1[r] + bias1[r];
                h0 = h0 > 0.f ? h0 : 0.f;
                h1 = h1 > 0.f ? h1 : 0.f;
                a2u.us[r]     = f2bf(h0);   // k-local quad*8 + r      <-> chunk-row quad*4+r
                a2u.us[r + 4] = f2bf(h1);   // k-local quad*8 + 4 + r  <-> chunk-row 16+quad*4+r
            }
            short8 a2 = a2u.s8;
#pragma unroll
            for (int nt = 0; nt < 4; ++nt) {
                short8 b2f = *(const short8*)&sW2[(nt * 16 + m) * W2T_LD + nc * 32 + quad * 8];
                oacc[nt] = __builtin_amdgcn_mfma_f32_16x16x32_bf16(a2, b2f, oacc[nt], 0, 0, 0);
            }
        }

        // epilogue: D layout row=quad*4+r (edge), col=nt*16+m
        float* po = out + (long)tile * 16 * 64;
#pragma unroll
        for (int nt = 0; nt < 4; ++nt) {
#pragma unroll
            for (int r = 0; r < 4; ++r) {
                po[(quad * 4 + r) * 64 + nt * 16 + m] = oacc[nt][r] + b2v[nt];
            }
        }
    }
}

extern "C" void kernel_launch(void* const* d_in, const int* in_sizes, int n_in,
                              void* d_out, int out_size, void* d_ws, size_t ws_size,
                              hipStream_t stream) {
    const float* x   = (const float*)d_in[0];
    const float* ea  = (const float*)d_in[1];
    const float* u   = (const float*)d_in[2];
    const float* W1  = (const float*)d_in[3];
    const float* b1  = (const float*)d_in[4];
    const float* W2  = (const float*)d_in[5];
    const float* b2  = (const float*)d_in[6];
    const int*   ei  = (const int*)d_in[7];
    float* out = (float*)d_out;

    unsigned short* w1t = (unsigned short*)((char*)d_ws + WS_W1T_OFF);
    unsigned short* w2t = (unsigned short*)((char*)d_ws + WS_W2T_OFF);
    float*          b1p = (float*)((char*)d_ws + WS_B1P_OFF);

    hipLaunchKernelGGL(edgeblk_prep, dim3(192), dim3(256), 0, stream,
                       W1, b1, W2, u, w1t, w2t, b1p);
    hipLaunchKernelGGL(edgeblk_mlp, dim3(GRID_MAIN), dim3(BLOCK_T), 0, stream,
                       x, ea, ei, w1t, w2t, b1p, b2, out);
}